// Round 1
// baseline (146.184 us; speedup 1.0000x reference)
//
#include <hip/hip_runtime.h>

// Problem constants (fixed by setup_inputs): input (4,3,768,768) f32,
// out_h = out_w = 384, KW = 4.0 -> P = 6, scale = 384/768 = 0.5 both axes.
#define BB 4
#define CC 3
#define IH 768
#define IW 768
#define OH 384
#define OW 384
#define PP 6

#define RES_N   (BB * CC * OH * OW)        // 1,769,472 floats
#define KER_N   (BB * OH * OW * PP * PP)   // 21,233,664 floats

// Catmull-Rom style cubic (a = -0.5), matches reference _cubic exactly.
__device__ __forceinline__ float cubic_w(float x) {
    float a  = fabsf(x);
    float a2 = a * a;
    float a3 = a2 * a;
    if (a <= 1.0f) return 1.5f * a3 - 2.5f * a2 + 1.0f;
    if (a <= 2.0f) return -0.5f * a3 + 2.5f * a2 - 4.0f * a + 2.0f;
    return 0.0f;
}

// Replicates _axis_indices_offsets + _cubic + per-axis normalization.
// o is 0-based output index. scale = out/in = 0.5, inv_scale = in/out = 2.
__device__ __forceinline__ void axis_weights(int o, float scale, float inv_scale,
                                             int in_s, int* idx, float* w) {
    float x = (float)(o + 1);
    float u = x * inv_scale + 0.5f * (1.0f - inv_scale);
    float left = floorf(u - 2.0f);          // KW/2 = 2
    float sum = 0.0f;
    #pragma unroll
    for (int p = 0; p < PP; ++p) {
        float idxf = left + (float)p;
        float off  = u - idxf;
        float cl   = fminf(fmaxf(idxf, 1.0f), (float)in_s);
        idx[p] = (int)cl - 1;
        w[p] = cubic_w(off * scale);
        sum += w[p];
    }
    // wmat/(sum_p sum_q wh*ww) == (wh/sum_wh) (x) (ww/sum_ww)
    float inv = 1.0f / sum;
    #pragma unroll
    for (int p = 0; p < PP; ++p) w[p] *= inv;
}

// One thread per output pixel of res: (bc, i, j).
__global__ __launch_bounds__(256) void bicubic_res_kernel(
        const float* __restrict__ in, float* __restrict__ out) {
    int t = blockIdx.x * blockDim.x + threadIdx.x;
    if (t >= RES_N) return;
    int j   = t % OW;
    int rem = t / OW;
    int i   = rem % OH;
    int bc  = rem / OH;

    int   ri[PP], ci[PP];
    float wh[PP], ww[PP];
    axis_weights(i, 0.5f, 2.0f, IH, ri, wh);
    axis_weights(j, 0.5f, 2.0f, IW, ci, ww);

    const float* base = in + (size_t)bc * (IH * IW);
    float acc = 0.0f;
    #pragma unroll
    for (int p = 0; p < PP; ++p) {
        const float* row = base + (size_t)ri[p] * IW;
        float rsum = 0.0f;
        #pragma unroll
        for (int q = 0; q < PP; ++q)
            rsum = fmaf(ww[q], row[ci[q]], rsum);
        acc = fmaf(wh[p], rsum, acc);
    }
    out[t] = acc;
}

// One block per (b, i) output row of the broadcast weight tensor.
// Writes OW*36 = 13824 floats = 3456 float4 per block, fully coalesced.
__global__ __launch_bounds__(256) void bicubic_wmat_kernel(float* __restrict__ kout) {
    int b = blockIdx.x / OH;
    int i = blockIdx.x % OH;

    __shared__ float s_ww[OW * PP];   // normalized column weights, 9216 B
    __shared__ float s_wh[PP];

    for (int j = threadIdx.x; j < OW; j += blockDim.x) {
        int   ci[PP];
        float w[PP];
        axis_weights(j, 0.5f, 2.0f, IW, ci, w);
        #pragma unroll
        for (int q = 0; q < PP; ++q) s_ww[j * PP + q] = w[q];
    }
    if (threadIdx.x == 0) {
        int   ri[PP];
        float w[PP];
        axis_weights(i, 0.5f, 2.0f, IH, ri, w);
        #pragma unroll
        for (int p = 0; p < PP; ++p) s_wh[p] = w[p];
    }
    __syncthreads();

    float4* dst = (float4*)(kout + (size_t)(b * OH + i) * (OW * PP * PP));
    const int NF4 = OW * PP * PP / 4;   // 3456
    for (int f = threadIdx.x; f < NF4; f += blockDim.x) {
        int e = f * 4;
        int j = e / 36;
        int k = e % 36;          // in {0,4,...,32}; all 4 elems same j
        float v[4];
        #pragma unroll
        for (int tt = 0; tt < 4; ++tt) {
            int kk = k + tt;
            int p = kk / PP;
            int q = kk - p * PP;
            v[tt] = s_wh[p] * s_ww[j * PP + q];
        }
        float4 o;
        o.x = v[0]; o.y = v[1]; o.z = v[2]; o.w = v[3];
        dst[f] = o;
    }
}

extern "C" void kernel_launch(void* const* d_in, const int* in_sizes, int n_in,
                              void* d_out, int out_size, void* d_ws, size_t ws_size,
                              hipStream_t stream) {
    const float* input = (const float*)d_in[0];
    float* out = (float*)d_out;
    float* res  = out;            // first RES_N floats
    float* kout = out + RES_N;    // then KER_N floats

    // res first: keep input warm in L2 before the big streaming weight write.
    {
        int blocks = (RES_N + 255) / 256;
        bicubic_res_kernel<<<blocks, 256, 0, stream>>>(input, res);
    }
    {
        int blocks = BB * OH;     // 1536
        bicubic_wmat_kernel<<<blocks, 256, 0, stream>>>(kout);
    }
}

// Round 2
// 119.154 us; speedup vs baseline: 1.2268x; 1.2268x over previous
//
#include <hip/hip_runtime.h>

// Bicubic 2x downsample, input (4,3,768,768) f32 -> res (4,3,384,384) +
// broadcast weight tensor (4,1,384,384,36).
//
// KEY FACT: scale = 0.5 exactly => u = 2j+1.5, left = 2j-1, off = 2.5-q
// EXACTLY in f32 for every position (clipping only touches indices).
// So the normalized 6-tap filter is a position-independent constant on both
// axes, taps are 6 CONSECUTIVE rows/cols (clamped at borders), and the
// entire 85 MB weight tensor is one repeating 36-float (144 B) pattern.

#define IHW 768
#define OHW 384
#define PP  6
#define NBC 12                      // 4*3 batch*channel planes
#define RES_N  (NBC * OHW * OHW)            // 1,769,472
#define KER_N  (4 * OHW * OHW * PP * PP)    // 21,233,664
#define KER_F4 (KER_N / 4)                  // 5,308,416

#define SX_N 96                     // 4-wide output patches per row
#define SY_N 192                    // 2-tall output patches per col
#define RES_THREADS (NBC * SX_N * SY_N)     // 221,184
#define RES_BLOCKS  (RES_THREADS / 256)     // 864
#define WMAT_THREADS 147456                 // 9 * 16384 -> stride % 9 == 0
#define WMAT_BLOCKS  (WMAT_THREADS / 256)   // 576

__device__ __forceinline__ float cubic_w(float x) {
    float a  = fabsf(x);
    float a2 = a * a, a3 = a2 * a;
    float r1 = 1.5f * a3 - 2.5f * a2 + 1.0f;
    float r2 = -0.5f * a3 + 2.5f * a2 - 4.0f * a + 2.0f;
    return a <= 1.0f ? r1 : (a <= 2.0f ? r2 : 0.0f);
}

// Position-independent normalized 6-tap filter (same for rows and cols).
__device__ __forceinline__ void calc_wn(float wn[PP]) {
    float s = 0.0f;
    #pragma unroll
    for (int q = 0; q < PP; ++q) {
        wn[q] = cubic_w((2.5f - (float)q) * 0.5f);
        s += wn[q];
    }
    float inv = 1.0f / s;
    #pragma unroll
    for (int q = 0; q < PP; ++q) wn[q] *= inv;
}

__global__ __launch_bounds__(256) void bicubic_fused_kernel(
        const float* __restrict__ in, float* __restrict__ out) {
    float* res  = out;
    float* kout = out + RES_N;

    float wn[PP];
    calc_wn(wn);

    int blk = blockIdx.x;
    if (blk < RES_BLOCKS) {
        // ---- res: each thread computes a 4-wide x 2-tall output patch ----
        int g   = blk * 256 + threadIdx.x;          // < RES_THREADS exactly
        int sx  = g % SX_N;
        int t1  = g / SX_N;
        int sy  = t1 % SY_N;
        int bc  = t1 / SY_N;
        int j0  = 4 * sx;                           // output cols j0..j0+3
        int i0  = 2 * sy;                           // output rows i0..i0+1
        int col0 = 8 * sx - 4;                      // first loaded input col
        const float* base = in + (size_t)bc * (IHW * IHW);
        bool edge = (sx == 0) | (sx == SX_N - 1);

        float acc[2][4] = {{0.f,0.f,0.f,0.f},{0.f,0.f,0.f,0.f}};

        #pragma unroll
        for (int k = 0; k < 8; ++k) {
            int row = 4 * sy - 2 + k;
            row = min(max(row, 0), IHW - 1);        // clamp = reference clip
            const float* rp = base + (size_t)row * IHW;

            float v[16];
            if (edge) {
                #pragma unroll
                for (int m = 0; m < 16; ++m) {
                    int c = col0 + m;
                    c = min(max(c, 0), IHW - 1);
                    v[m] = rp[c];
                }
            } else {
                const float4* p4 = (const float4*)(rp + col0);  // 16B aligned
                float4 A = p4[0], B = p4[1], C = p4[2], D = p4[3];
                v[0]=A.x; v[1]=A.y; v[2]=A.z; v[3]=A.w;
                v[4]=B.x; v[5]=B.y; v[6]=B.z; v[7]=B.w;
                v[8]=C.x; v[9]=C.y; v[10]=C.z; v[11]=C.w;
                v[12]=D.x; v[13]=D.y; v[14]=D.z; v[15]=D.w;
            }

            #pragma unroll
            for (int c = 0; c < 4; ++c) {
                // horizontal 6-tap at output col j0+c: local cols 2c+2 .. 2c+7
                float h = wn[0] * v[2*c + 2];
                h = fmaf(wn[1], v[2*c + 3], h);
                h = fmaf(wn[2], v[2*c + 4], h);
                h = fmaf(wn[3], v[2*c + 5], h);
                h = fmaf(wn[4], v[2*c + 6], h);
                h = fmaf(wn[5], v[2*c + 7], h);
                // vertical: input row k feeds output o when p = k-2o in [0,5]
                #pragma unroll
                for (int o = 0; o < 2; ++o) {
                    int p = k - 2 * o;
                    if (p >= 0 && p < PP)
                        acc[o][c] = fmaf(wn[p], h, acc[o][c]);
                }
            }
        }

        #pragma unroll
        for (int o = 0; o < 2; ++o) {
            float4 r;
            r.x = acc[o][0]; r.y = acc[o][1]; r.z = acc[o][2]; r.w = acc[o][3];
            *(float4*)(res + ((size_t)(bc * OHW + i0 + o) * OHW + j0)) = r;
        }
    } else {
        // ---- wmat: stream one repeating 9-float4 pattern over 85 MB ----
        int t = (blk - RES_BLOCKS) * 256 + threadIdx.x;   // < WMAT_THREADS
        int r = t % 9;            // fixed per thread since stride % 9 == 0
        float4 pat;
        // float4 #r of the 36-float pattern wn[p]*wn[q], kk = 4r+j, p=kk/6,q=kk%6
        switch (r) {
            case 0: pat = make_float4(wn[0]*wn[0], wn[0]*wn[1], wn[0]*wn[2], wn[0]*wn[3]); break;
            case 1: pat = make_float4(wn[0]*wn[4], wn[0]*wn[5], wn[1]*wn[0], wn[1]*wn[1]); break;
            case 2: pat = make_float4(wn[1]*wn[2], wn[1]*wn[3], wn[1]*wn[4], wn[1]*wn[5]); break;
            case 3: pat = make_float4(wn[2]*wn[0], wn[2]*wn[1], wn[2]*wn[2], wn[2]*wn[3]); break;
            case 4: pat = make_float4(wn[2]*wn[4], wn[2]*wn[5], wn[3]*wn[0], wn[3]*wn[1]); break;
            case 5: pat = make_float4(wn[3]*wn[2], wn[3]*wn[3], wn[3]*wn[4], wn[3]*wn[5]); break;
            case 6: pat = make_float4(wn[4]*wn[0], wn[4]*wn[1], wn[4]*wn[2], wn[4]*wn[3]); break;
            case 7: pat = make_float4(wn[4]*wn[4], wn[4]*wn[5], wn[5]*wn[0], wn[5]*wn[1]); break;
            default: pat = make_float4(wn[5]*wn[2], wn[5]*wn[3], wn[5]*wn[4], wn[5]*wn[5]); break;
        }
        float4* k4 = (float4*)kout;
        for (int f = t; f < KER_F4; f += WMAT_THREADS)    // 36 iters, coalesced
            k4[f] = pat;
    }
}

extern "C" void kernel_launch(void* const* d_in, const int* in_sizes, int n_in,
                              void* d_out, int out_size, void* d_ws, size_t ws_size,
                              hipStream_t stream) {
    const float* input = (const float*)d_in[0];
    float* out = (float*)d_out;
    bicubic_fused_kernel<<<RES_BLOCKS + WMAT_BLOCKS, 256, 0, stream>>>(input, out);
}